// Round 9
// baseline (550.959 us; speedup 1.0000x reference)
//
#include <hip/hip_runtime.h>
#include <hip/hip_bf16.h>
#include <math.h>

#define H 128
#define NTPB 256
#define CHUNK 1024  // elements per scan block (256 threads x 4)
#define SRC_MASK 0x1FFFFu
#define WSCALE (1.0f / 32767.0f)

typedef __attribute__((ext_vector_type(8))) short short8;
typedef __attribute__((ext_vector_type(4))) float floatx4;

__device__ __forceinline__ void atomAddF(float* p, float v) {
    __hip_atomic_fetch_add(p, v, __ATOMIC_RELAXED, __HIP_MEMORY_SCOPE_AGENT);
}

__device__ __forceinline__ short f2bf(float v) {
    __hip_bfloat16 b = __float2bfloat16(v);
    return __builtin_bit_cast(short, b);
}

// accumulate one 256B bf16 row chunk (uint4 = 8 bf16) scaled by wgt
__device__ __forceinline__ void acc8(float* acc, uint4 p, float wgt) {
    acc[0] += __uint_as_float(p.x << 16) * wgt;
    acc[1] += __uint_as_float(p.x & 0xffff0000u) * wgt;
    acc[2] += __uint_as_float(p.y << 16) * wgt;
    acc[3] += __uint_as_float(p.y & 0xffff0000u) * wgt;
    acc[4] += __uint_as_float(p.z << 16) * wgt;
    acc[5] += __uint_as_float(p.z & 0xffff0000u) * wgt;
    acc[6] += __uint_as_float(p.w << 16) * wgt;
    acc[7] += __uint_as_float(p.w & 0xffff0000u) * wgt;
}

// merged prologue: deg counting (4 edges/thread), x -> float4 pack, W2 -> bf16 frag pack
__global__ void pre_kernel(const int* __restrict__ ei, int E, int* __restrict__ deg,
                           const float* __restrict__ x, float4* __restrict__ x4, int N,
                           const float* __restrict__ W2, __hip_bfloat16* __restrict__ Bp) {
    int gt = blockIdx.x * blockDim.x + threadIdx.x;
    int e4 = gt * 4;
    if (e4 + 4 <= E) {
        int4 d = *(const int4*)(ei + E + e4);
        atomicAdd(&deg[d.x], 1);
        atomicAdd(&deg[d.y], 1);
        atomicAdd(&deg[d.z], 1);
        atomicAdd(&deg[d.w], 1);
    } else {
        for (int e = e4; e < E; ++e) atomicAdd(&deg[ei[E + e]], 1);
    }
    if (gt < N) x4[gt] = make_float4(x[3 * gt + 0], x[3 * gt + 1], x[3 * gt + 2], 0.f);
    if (gt < 2048) {  // bf16 B-fragment pack for mfma_f32_16x16x32_bf16
        int frag = gt >> 6, lane = gt & 63;
        int nt = frag >> 2, c = frag & 3, quad = lane >> 4, m16 = lane & 15;
#pragma unroll
        for (int jj = 0; jj < 8; jj++) {
            int k = c * 32 + quad * 8 + jj;
            Bp[gt * 8 + jj] = __float2bfloat16(W2[k * H + nt * 16 + m16]);
        }
    }
}

// ---- exclusive scan of deg -> rowptr ----
__global__ void scan_partial(const int* __restrict__ deg, int N, int* __restrict__ partial) {
    __shared__ int sd[NTPB];
    int b = blockIdx.x, t = threadIdx.x;
    int base = b * CHUNK + t * 4;
    int s = 0;
#pragma unroll
    for (int k = 0; k < 4; k++) { int i = base + k; if (i < N) s += deg[i]; }
    sd[t] = s; __syncthreads();
    for (int off = NTPB / 2; off > 0; off >>= 1) {
        if (t < off) sd[t] += sd[t + off];
        __syncthreads();
    }
    if (t == 0) partial[b] = sd[0];
}

// wave-parallel scan of block sums (nb <= 128); also writes rowptr[N] = E
__global__ void scan_tops(const int* __restrict__ partial, int nb,
                          int* __restrict__ pscan, int* __restrict__ rowptr, int N) {
    __shared__ int sd[128];
    int t = threadIdx.x;
    int v = (t < nb) ? partial[t] : 0;
    sd[t] = v; __syncthreads();
    for (int s = 1; s < 128; s <<= 1) {
        int u = (t >= s) ? sd[t - s] : 0;
        __syncthreads();
        sd[t] += u;
        __syncthreads();
    }
    if (t < nb) pscan[t] = sd[t] - v;  // exclusive
    if (t == 0) rowptr[N] = sd[127];
}

// also emits dinv
__global__ void scan_apply(const int* __restrict__ deg, int N, const int* __restrict__ pscan,
                           int* __restrict__ rowptr, int* __restrict__ cursor,
                           float* __restrict__ dinv) {
    __shared__ int sd[NTPB];
    int b = blockIdx.x, t = threadIdx.x;
    int base = b * CHUNK + t * 4;
    int d0 = 0, d1 = 0, d2 = 0, d3 = 0;
    if (base + 0 < N) d0 = deg[base + 0];
    if (base + 1 < N) d1 = deg[base + 1];
    if (base + 2 < N) d2 = deg[base + 2];
    if (base + 3 < N) d3 = deg[base + 3];
    int tsum = d0 + d1 + d2 + d3;
    sd[t] = tsum; __syncthreads();
    for (int s = 1; s < NTPB; s <<= 1) {
        int v = (t >= s) ? sd[t - s] : 0;
        __syncthreads();
        sd[t] += v;
        __syncthreads();
    }
    int p0 = sd[t] - tsum + pscan[b];
    int p1 = p0 + d0, p2 = p1 + d1, p3 = p2 + d2;
    if (base + 0 < N) { rowptr[base + 0] = p0; cursor[base + 0] = p0; dinv[base + 0] = rsqrtf((float)(d0 + 1)); }
    if (base + 1 < N) { rowptr[base + 1] = p1; cursor[base + 1] = p1; dinv[base + 1] = rsqrtf((float)(d1 + 1)); }
    if (base + 2 < N) { rowptr[base + 2] = p2; cursor[base + 2] = p2; dinv[base + 2] = rsqrtf((float)(d2 + 1)); }
    if (base + 3 < N) { rowptr[base + 3] = p3; cursor[base + 3] = p3; dinv[base + 3] = rsqrtf((float)(d3 + 1)); }
}

// bucket-scatter: dst-grouped packed edge = (w*32767)<<17 | src ; 4 edges/thread
__global__ void scatter_kernel(const int* __restrict__ ei, int E, const float* __restrict__ dinv,
                               int* __restrict__ cursor, unsigned* __restrict__ csr) {
    int e4 = (blockIdx.x * blockDim.x + threadIdx.x) * 4;
    if (e4 + 4 <= E) {
        int4 s = *(const int4*)(ei + e4);
        int4 d = *(const int4*)(ei + E + e4);
        float ws0 = dinv[s.x], ws1 = dinv[s.y], ws2 = dinv[s.z], ws3 = dinv[s.w];
        float wd0 = dinv[d.x], wd1 = dinv[d.y], wd2 = dinv[d.z], wd3 = dinv[d.w];
        int p0 = atomicAdd(&cursor[d.x], 1);
        int p1 = atomicAdd(&cursor[d.y], 1);
        int p2 = atomicAdd(&cursor[d.z], 1);
        int p3 = atomicAdd(&cursor[d.w], 1);
        csr[p0] = ((unsigned)(ws0 * wd0 * 32767.0f + 0.5f) << 17) | (unsigned)s.x;
        csr[p1] = ((unsigned)(ws1 * wd1 * 32767.0f + 0.5f) << 17) | (unsigned)s.y;
        csr[p2] = ((unsigned)(ws2 * wd2 * 32767.0f + 0.5f) << 17) | (unsigned)s.z;
        csr[p3] = ((unsigned)(ws3 * wd3 * 32767.0f + 0.5f) << 17) | (unsigned)s.w;
    } else {
        for (int e = e4; e < E; ++e) {
            int s = ei[e], d = ei[E + e];
            int pos = atomicAdd(&cursor[d], 1);
            float w = dinv[s] * dinv[d];
            csr[pos] = ((unsigned)(w * 32767.0f + 0.5f) << 17) | (unsigned)s;
        }
    }
}

// layer-1 CSR gather on float4-padded x: one dwordx4 per edge, 4-edge unroll
__global__ void l1_gather(const float4* __restrict__ x4, const float* __restrict__ dinv,
                          const int* __restrict__ rowptr, const unsigned* __restrict__ csr,
                          float* __restrict__ aggx, int N) {
    int n = blockIdx.x * blockDim.x + threadIdx.x;
    if (n >= N) return;
    float di = dinv[n], d2 = di * di;
    float4 xs = x4[n];
    float a0 = xs.x * d2, a1 = xs.y * d2, a2 = xs.z * d2;
    int beg = rowptr[n], end = rowptr[n + 1];
    int i = beg;
    for (; i + 4 <= end; i += 4) {
        unsigned c0 = csr[i], c1 = csr[i + 1], c2 = csr[i + 2], c3 = csr[i + 3];
        float4 v0 = x4[c0 & SRC_MASK];
        float4 v1 = x4[c1 & SRC_MASK];
        float4 v2 = x4[c2 & SRC_MASK];
        float4 v3 = x4[c3 & SRC_MASK];
        float w0 = (float)(c0 >> 17) * WSCALE, w1 = (float)(c1 >> 17) * WSCALE;
        float w2 = (float)(c2 >> 17) * WSCALE, w3 = (float)(c3 >> 17) * WSCALE;
        a0 += v0.x * w0 + v1.x * w1 + v2.x * w2 + v3.x * w3;
        a1 += v0.y * w0 + v1.y * w1 + v2.y * w2 + v3.y * w3;
        a2 += v0.z * w0 + v1.z * w1 + v2.z * w2 + v3.z * w3;
    }
    for (; i < end; ++i) {
        unsigned c = csr[i];
        float4 v = x4[c & SRC_MASK];
        float w = (float)(c >> 17) * WSCALE;
        a0 += v.x * w; a1 += v.y * w; a2 += v.z * w;
    }
    aggx[3 * n + 0] = a0; aggx[3 * n + 1] = a1; aggx[3 * n + 2] = a2;
}

// MFMA gemm: one wave per 16-row tile. A = relu(aggx@W1+b1) built in regs (bf16),
// B = pre-packed W2 frags, D -> bf16 hB.
__global__ void gemm2_mfma(const float* __restrict__ aggx, const float* __restrict__ W1,
                           const float* __restrict__ b1, const __hip_bfloat16* __restrict__ Bp,
                           __hip_bfloat16* __restrict__ hBb, int N) {
    int wave = threadIdx.x >> 6, lane = threadIdx.x & 63;
    int quad = lane >> 4, m16 = lane & 15;
    int tile = blockIdx.x * 4 + wave;
    int rowbase = tile * 16;
    if (rowbase >= N) return;
    int m = rowbase + m16;
    float a0 = 0.f, a1 = 0.f, a2 = 0.f;
    if (m < N) { a0 = aggx[3 * m]; a1 = aggx[3 * m + 1]; a2 = aggx[3 * m + 2]; }
    short8 af[4];
#pragma unroll
    for (int c = 0; c < 4; c++) {
#pragma unroll
        for (int jj = 0; jj < 8; jj++) {
            int k = c * 32 + quad * 8 + jj;
            float h = fmaxf(a0 * W1[k] + a1 * W1[H + k] + a2 * W1[2 * H + k] + b1[k], 0.f);
            af[c][jj] = f2bf(h);
        }
    }
    const short8* bp = (const short8*)Bp;
    floatx4 acc[8];
#pragma unroll
    for (int nt = 0; nt < 8; nt++) acc[nt] = (floatx4){0.f, 0.f, 0.f, 0.f};
#pragma unroll
    for (int nt = 0; nt < 8; nt++) {
#pragma unroll
        for (int c = 0; c < 4; c++) {
            short8 bf = bp[(nt * 4 + c) * 64 + lane];
            acc[nt] = __builtin_amdgcn_mfma_f32_16x16x32_bf16(af[c], bf, acc[nt], 0, 0, 0);
        }
    }
#pragma unroll
    for (int nt = 0; nt < 8; nt++) {
#pragma unroll
        for (int reg = 0; reg < 4; reg++) {
            int row = rowbase + quad * 4 + reg;
            int col = nt * 16 + m16;
            if (row < N) hBb[(size_t)row * H + col] = __float2bfloat16(acc[nt][reg]);
        }
    }
}

// layer-2 gather: one 16-lane group per NODE (4 nodes/wave). Row read = 16 lanes
// x uint4 (256 B). 4-edge unroll. Near the random-line service wall (~167us floor).
__global__ __launch_bounds__(NTPB, 8) void gather_pool(
        const uint4* __restrict__ hB4, const float* __restrict__ dinv,
        const int* __restrict__ rowptr, const unsigned* __restrict__ csr,
        const float* __restrict__ b2, const float* __restrict__ Wc,
        const int* __restrict__ batch,
        float* __restrict__ gsum, int* __restrict__ gcnt, int N) {
    __shared__ float sb2[H];
    __shared__ float swc[H];
    int t = threadIdx.x;
    if (t < H) { sb2[t] = b2[t]; swc[t] = Wc[t]; }
    __syncthreads();
    int grp = t >> 4;
    int l16 = t & 15;
    int node = blockIdx.x * 16 + grp;
    if (node >= N) return;
    float acc[8];
#pragma unroll
    for (int j = 0; j < 8; j++) acc[j] = 0.f;
    int beg = rowptr[node], end = rowptr[node + 1];
    for (int i = beg; i < end; i += 4) {
        int rem = end - i;
        unsigned c0 = csr[i];
        unsigned c1 = (rem > 1) ? csr[i + 1] : 0u;
        unsigned c2 = (rem > 2) ? csr[i + 2] : 0u;
        unsigned c3 = (rem > 3) ? csr[i + 3] : 0u;
        uint4 p0 = hB4[(size_t)(c0 & SRC_MASK) * 16 + l16];
        uint4 p1 = hB4[(size_t)(c1 & SRC_MASK) * 16 + l16];
        uint4 p2 = hB4[(size_t)(c2 & SRC_MASK) * 16 + l16];
        uint4 p3 = hB4[(size_t)(c3 & SRC_MASK) * 16 + l16];
        acc8(acc, p0, (float)(c0 >> 17) * WSCALE);
        acc8(acc, p1, (float)(c1 >> 17) * WSCALE);
        acc8(acc, p2, (float)(c2 >> 17) * WSCALE);
        acc8(acc, p3, (float)(c3 >> 17) * WSCALE);
    }
    float di = dinv[node];
    uint4 ps = hB4[(size_t)node * 16 + l16];
    acc8(acc, ps, di * di);
    float dot = 0.f;
#pragma unroll
    for (int j = 0; j < 8; j++) {
        float v = fmaxf(acc[j] + sb2[8 * l16 + j], 0.f);
        dot += v * swc[8 * l16 + j];
    }
    dot += __shfl_xor(dot, 1);
    dot += __shfl_xor(dot, 2);
    dot += __shfl_xor(dot, 4);
    dot += __shfl_xor(dot, 8);
    if (l16 == 0) {
        int gidx = batch[node];
        atomAddF(&gsum[gidx], dot);
        atomicAdd(&gcnt[gidx], 1);
    }
}

__global__ void out_kernel(const float* __restrict__ gsum, const int* __restrict__ gcnt,
                           const float* __restrict__ bc, float* __restrict__ out, int G) {
    int g = blockIdx.x * blockDim.x + threadIdx.x;
    if (g >= G) return;
    float c = fmaxf((float)gcnt[g], 1.f);
    float logit = gsum[g] / c + bc[0];
    out[g] = 1.f / (1.f + expf(-logit));
}

extern "C" void kernel_launch(void* const* d_in, const int* in_sizes, int n_in,
                              void* d_out, int out_size, void* d_ws, size_t ws_size,
                              hipStream_t stream) {
    const float* x     = (const float*)d_in[0];
    const int*   ei    = (const int*)d_in[1];
    const int*   batch = (const int*)d_in[2];
    const float* W1    = (const float*)d_in[3];
    const float* b1    = (const float*)d_in[4];
    const float* W2    = (const float*)d_in[5];
    const float* b2    = (const float*)d_in[6];
    const float* Wc    = (const float*)d_in[7];
    const float* bc    = (const float*)d_in[8];
    float* out = (float*)d_out;

    int N = in_sizes[2];
    int E = in_sizes[1] / 2;
    int G = out_size;
    int NB = (N + CHUNK - 1) / CHUNK;

    char* ws = (char*)d_ws;
    size_t off = 0;
    auto alloc = [&](size_t bytes) {
        void* p = ws + off;
        off += (bytes + 255) & ~(size_t)255;
        return p;
    };
    __hip_bfloat16* hBb = (__hip_bfloat16*)alloc((size_t)N * H * sizeof(__hip_bfloat16));
    float* aggx   = (float*)alloc((size_t)N * 3 * sizeof(float));
    float4* x4    = (float4*)alloc((size_t)N * sizeof(float4));
    // deg/gsum/gcnt contiguous -> single memset
    int*   deg    = (int*)  alloc((size_t)N * sizeof(int));
    float* gsum   = (float*)alloc((size_t)G * sizeof(float));
    int*   gcnt   = (int*)  alloc((size_t)G * sizeof(int));
    char*  zero_end = ws + off;
    int*   rowptr = (int*)  alloc((size_t)(N + 1) * sizeof(int));
    int*   cursor = (int*)  alloc((size_t)N * sizeof(int));
    float* dinv   = (float*)alloc((size_t)N * sizeof(float));
    unsigned* csr = (unsigned*)alloc((size_t)E * sizeof(unsigned));
    __hip_bfloat16* Bp = (__hip_bfloat16*)alloc((size_t)H * H * sizeof(__hip_bfloat16));
    int*   partial= (int*)  alloc((size_t)NB * sizeof(int));
    int*   pscan  = (int*)  alloc((size_t)NB * sizeof(int));

    (void)hipMemsetAsync(deg, 0, (size_t)(zero_end - (char*)deg), stream);

    {
        int nthr = (E + 3) / 4;
        if (nthr < N) nthr = N;
        pre_kernel<<<(nthr + NTPB - 1) / NTPB, NTPB, 0, stream>>>(ei, E, deg, x, x4, N, W2, Bp);
    }

    scan_partial<<<NB, NTPB, 0, stream>>>(deg, N, partial);
    scan_tops<<<1, 128, 0, stream>>>(partial, NB, pscan, rowptr, N);
    scan_apply<<<NB, NTPB, 0, stream>>>(deg, N, pscan, rowptr, cursor, dinv);

    {
        int nthr4 = (E + 3) / 4;
        scatter_kernel<<<(nthr4 + NTPB - 1) / NTPB, NTPB, 0, stream>>>(ei, E, dinv, cursor, csr);
    }

    l1_gather<<<(N + NTPB - 1) / NTPB, NTPB, 0, stream>>>(x4, dinv, rowptr, csr, aggx, N);

    {
        int ntiles = (N + 15) / 16;
        gemm2_mfma<<<(ntiles + 3) / 4, NTPB, 0, stream>>>(aggx, W1, b1, Bp, hBb, N);
    }

    gather_pool<<<(N + 15) / 16, NTPB, 0, stream>>>(
        (const uint4*)hBb, dinv, rowptr, csr, b2, Wc, batch, gsum, gcnt, N);

    out_kernel<<<(G + NTPB - 1) / NTPB, NTPB, 0, stream>>>(gsum, gcnt, bc, out, G);
}

// Round 10
// 539.449 us; speedup vs baseline: 1.0213x; 1.0213x over previous
//
#include <hip/hip_runtime.h>
#include <hip/hip_bf16.h>
#include <math.h>

#define H 128
#define NTPB 256
#define CHUNK 1024  // elements per scan block (256 threads x 4)
#define SRC_MASK 0x1FFFFu
#define WSCALE (1.0f / 32767.0f)

typedef __attribute__((ext_vector_type(8))) short short8;
typedef __attribute__((ext_vector_type(4))) float floatx4;

__device__ __forceinline__ void atomAddF(float* p, float v) {
    __hip_atomic_fetch_add(p, v, __ATOMIC_RELAXED, __HIP_MEMORY_SCOPE_AGENT);
}

__device__ __forceinline__ short f2bf(float v) {
    __hip_bfloat16 b = __float2bfloat16(v);
    return __builtin_bit_cast(short, b);
}

// accumulate one 256B bf16 row chunk (uint4 = 8 bf16) scaled by wgt
__device__ __forceinline__ void acc8(float* acc, uint4 p, float wgt) {
    acc[0] += __uint_as_float(p.x << 16) * wgt;
    acc[1] += __uint_as_float(p.x & 0xffff0000u) * wgt;
    acc[2] += __uint_as_float(p.y << 16) * wgt;
    acc[3] += __uint_as_float(p.y & 0xffff0000u) * wgt;
    acc[4] += __uint_as_float(p.z << 16) * wgt;
    acc[5] += __uint_as_float(p.z & 0xffff0000u) * wgt;
    acc[6] += __uint_as_float(p.w << 16) * wgt;
    acc[7] += __uint_as_float(p.w & 0xffff0000u) * wgt;
}

// deg[d] = number of in-edges; 4 edges/thread via int4
__global__ void deg_kernel(const int* __restrict__ ei, int E, int* __restrict__ deg) {
    int e4 = (blockIdx.x * blockDim.x + threadIdx.x) * 4;
    if (e4 + 4 <= E) {
        int4 d = *(const int4*)(ei + E + e4);
        atomicAdd(&deg[d.x], 1);
        atomicAdd(&deg[d.y], 1);
        atomicAdd(&deg[d.z], 1);
        atomicAdd(&deg[d.w], 1);
    } else {
        for (int e = e4; e < E; ++e) atomicAdd(&deg[ei[E + e]], 1);
    }
}

// ---- exclusive scan of deg -> rowptr ----
__global__ void scan_partial(const int* __restrict__ deg, int N, int* __restrict__ partial) {
    __shared__ int sd[NTPB];
    int b = blockIdx.x, t = threadIdx.x;
    int base = b * CHUNK + t * 4;
    int s = 0;
#pragma unroll
    for (int k = 0; k < 4; k++) { int i = base + k; if (i < N) s += deg[i]; }
    sd[t] = s; __syncthreads();
    for (int off = NTPB / 2; off > 0; off >>= 1) {
        if (t < off) sd[t] += sd[t + off];
        __syncthreads();
    }
    if (t == 0) partial[b] = sd[0];
}

// wave-parallel scan of block sums (nb <= 128); also writes rowptr[N] = E
__global__ void scan_tops(const int* __restrict__ partial, int nb,
                          int* __restrict__ pscan, int* __restrict__ rowptr, int N) {
    __shared__ int sd[128];
    int t = threadIdx.x;
    int v = (t < nb) ? partial[t] : 0;
    sd[t] = v; __syncthreads();
    for (int s = 1; s < 128; s <<= 1) {
        int u = (t >= s) ? sd[t - s] : 0;
        __syncthreads();
        sd[t] += u;
        __syncthreads();
    }
    if (t < nb) pscan[t] = sd[t] - v;  // exclusive
    if (t == 0) rowptr[N] = sd[127];
}

// also emits dinv
__global__ void scan_apply(const int* __restrict__ deg, int N, const int* __restrict__ pscan,
                           int* __restrict__ rowptr, int* __restrict__ cursor,
                           float* __restrict__ dinv) {
    __shared__ int sd[NTPB];
    int b = blockIdx.x, t = threadIdx.x;
    int base = b * CHUNK + t * 4;
    int d0 = 0, d1 = 0, d2 = 0, d3 = 0;
    if (base + 0 < N) d0 = deg[base + 0];
    if (base + 1 < N) d1 = deg[base + 1];
    if (base + 2 < N) d2 = deg[base + 2];
    if (base + 3 < N) d3 = deg[base + 3];
    int tsum = d0 + d1 + d2 + d3;
    sd[t] = tsum; __syncthreads();
    for (int s = 1; s < NTPB; s <<= 1) {
        int v = (t >= s) ? sd[t - s] : 0;
        __syncthreads();
        sd[t] += v;
        __syncthreads();
    }
    int p0 = sd[t] - tsum + pscan[b];
    int p1 = p0 + d0, p2 = p1 + d1, p3 = p2 + d2;
    if (base + 0 < N) { rowptr[base + 0] = p0; cursor[base + 0] = p0; dinv[base + 0] = rsqrtf((float)(d0 + 1)); }
    if (base + 1 < N) { rowptr[base + 1] = p1; cursor[base + 1] = p1; dinv[base + 1] = rsqrtf((float)(d1 + 1)); }
    if (base + 2 < N) { rowptr[base + 2] = p2; cursor[base + 2] = p2; dinv[base + 2] = rsqrtf((float)(d2 + 1)); }
    if (base + 3 < N) { rowptr[base + 3] = p3; cursor[base + 3] = p3; dinv[base + 3] = rsqrtf((float)(d3 + 1)); }
}

// bucket-scatter: dst-grouped packed edge = (w*32767)<<17 | src ; 4 edges/thread
__global__ void scatter_kernel(const int* __restrict__ ei, int E, const float* __restrict__ dinv,
                               int* __restrict__ cursor, unsigned* __restrict__ csr) {
    int e4 = (blockIdx.x * blockDim.x + threadIdx.x) * 4;
    if (e4 + 4 <= E) {
        int4 s = *(const int4*)(ei + e4);
        int4 d = *(const int4*)(ei + E + e4);
        float ws0 = dinv[s.x], ws1 = dinv[s.y], ws2 = dinv[s.z], ws3 = dinv[s.w];
        float wd0 = dinv[d.x], wd1 = dinv[d.y], wd2 = dinv[d.z], wd3 = dinv[d.w];
        int p0 = atomicAdd(&cursor[d.x], 1);
        int p1 = atomicAdd(&cursor[d.y], 1);
        int p2 = atomicAdd(&cursor[d.z], 1);
        int p3 = atomicAdd(&cursor[d.w], 1);
        csr[p0] = ((unsigned)(ws0 * wd0 * 32767.0f + 0.5f) << 17) | (unsigned)s.x;
        csr[p1] = ((unsigned)(ws1 * wd1 * 32767.0f + 0.5f) << 17) | (unsigned)s.y;
        csr[p2] = ((unsigned)(ws2 * wd2 * 32767.0f + 0.5f) << 17) | (unsigned)s.z;
        csr[p3] = ((unsigned)(ws3 * wd3 * 32767.0f + 0.5f) << 17) | (unsigned)s.w;
    } else {
        for (int e = e4; e < E; ++e) {
            int s = ei[e], d = ei[E + e];
            int pos = atomicAdd(&cursor[d], 1);
            float w = dinv[s] * dinv[d];
            csr[pos] = ((unsigned)(w * 32767.0f + 0.5f) << 17) | (unsigned)s;
        }
    }
}

// pre-pack W2 into bf16 B-fragments for mfma_f32_16x16x32_bf16
__global__ void bpack_kernel(const float* __restrict__ W2, __hip_bfloat16* __restrict__ Bp) {
    int idx = blockIdx.x * blockDim.x + threadIdx.x;  // 0..2047
    if (idx >= 2048) return;
    int frag = idx >> 6, lane = idx & 63;
    int nt = frag >> 2, c = frag & 3, quad = lane >> 4, m16 = lane & 15;
#pragma unroll
    for (int jj = 0; jj < 8; jj++) {
        int k = c * 32 + quad * 8 + jj;
        Bp[idx * 8 + jj] = __float2bfloat16(W2[k * H + nt * 16 + m16]);
    }
}

// layer-1 CSR gather on raw x (3-wide), 4-edge unroll, packed csr  (R7-proven form)
__global__ void l1_gather(const float* __restrict__ x, const float* __restrict__ dinv,
                          const int* __restrict__ rowptr, const unsigned* __restrict__ csr,
                          float* __restrict__ aggx, int N) {
    int n = blockIdx.x * blockDim.x + threadIdx.x;
    if (n >= N) return;
    float di = dinv[n], d2 = di * di;
    float a0 = x[3 * n + 0] * d2, a1 = x[3 * n + 1] * d2, a2 = x[3 * n + 2] * d2;
    int beg = rowptr[n], end = rowptr[n + 1];
    int i = beg;
    for (; i + 4 <= end; i += 4) {
        unsigned c0 = csr[i], c1 = csr[i + 1], c2 = csr[i + 2], c3 = csr[i + 3];
        int s0 = c0 & SRC_MASK, s1 = c1 & SRC_MASK, s2 = c2 & SRC_MASK, s3 = c3 & SRC_MASK;
        float w0 = (float)(c0 >> 17) * WSCALE, w1 = (float)(c1 >> 17) * WSCALE;
        float w2 = (float)(c2 >> 17) * WSCALE, w3 = (float)(c3 >> 17) * WSCALE;
        float x00 = x[3 * s0], x01 = x[3 * s0 + 1], x02 = x[3 * s0 + 2];
        float x10 = x[3 * s1], x11 = x[3 * s1 + 1], x12 = x[3 * s1 + 2];
        float x20 = x[3 * s2], x21 = x[3 * s2 + 1], x22 = x[3 * s2 + 2];
        float x30 = x[3 * s3], x31 = x[3 * s3 + 1], x32 = x[3 * s3 + 2];
        a0 += x00 * w0 + x10 * w1 + x20 * w2 + x30 * w3;
        a1 += x01 * w0 + x11 * w1 + x21 * w2 + x31 * w3;
        a2 += x02 * w0 + x12 * w1 + x22 * w2 + x32 * w3;
    }
    for (; i < end; ++i) {
        unsigned c = csr[i];
        int s = c & SRC_MASK;
        float w = (float)(c >> 17) * WSCALE;
        a0 += x[3 * s + 0] * w;
        a1 += x[3 * s + 1] * w;
        a2 += x[3 * s + 2] * w;
    }
    aggx[3 * n + 0] = a0; aggx[3 * n + 1] = a1; aggx[3 * n + 2] = a2;
}

// MFMA gemm: one wave per 16-row tile. A = relu(aggx@W1+b1) built in regs (bf16),
// B = pre-packed W2 frags, D -> bf16 hB.
__global__ void gemm2_mfma(const float* __restrict__ aggx, const float* __restrict__ W1,
                           const float* __restrict__ b1, const __hip_bfloat16* __restrict__ Bp,
                           __hip_bfloat16* __restrict__ hBb, int N) {
    int wave = threadIdx.x >> 6, lane = threadIdx.x & 63;
    int quad = lane >> 4, m16 = lane & 15;
    int tile = blockIdx.x * 4 + wave;
    int rowbase = tile * 16;
    if (rowbase >= N) return;
    int m = rowbase + m16;
    float a0 = 0.f, a1 = 0.f, a2 = 0.f;
    if (m < N) { a0 = aggx[3 * m]; a1 = aggx[3 * m + 1]; a2 = aggx[3 * m + 2]; }
    short8 af[4];
#pragma unroll
    for (int c = 0; c < 4; c++) {
#pragma unroll
        for (int jj = 0; jj < 8; jj++) {
            int k = c * 32 + quad * 8 + jj;
            float h = fmaxf(a0 * W1[k] + a1 * W1[H + k] + a2 * W1[2 * H + k] + b1[k], 0.f);
            af[c][jj] = f2bf(h);
        }
    }
    const short8* bp = (const short8*)Bp;
    floatx4 acc[8];
#pragma unroll
    for (int nt = 0; nt < 8; nt++) acc[nt] = (floatx4){0.f, 0.f, 0.f, 0.f};
#pragma unroll
    for (int nt = 0; nt < 8; nt++) {
#pragma unroll
        for (int c = 0; c < 4; c++) {
            short8 bf = bp[(nt * 4 + c) * 64 + lane];
            acc[nt] = __builtin_amdgcn_mfma_f32_16x16x32_bf16(af[c], bf, acc[nt], 0, 0, 0);
        }
    }
#pragma unroll
    for (int nt = 0; nt < 8; nt++) {
#pragma unroll
        for (int reg = 0; reg < 4; reg++) {
            int row = rowbase + quad * 4 + reg;
            int col = nt * 16 + m16;
            if (row < N) hBb[(size_t)row * H + col] = __float2bfloat16(acc[nt][reg]);
        }
    }
}

// layer-2 gather: one 16-lane group per NODE (4 nodes/wave). Row read = 16 lanes
// x uint4 (256 B). 4-edge unroll. At the random-line service wall (~225us floor;
// five structurally different variants R2-R9 all land 225-260us).
__global__ __launch_bounds__(NTPB, 8) void gather_pool(
        const uint4* __restrict__ hB4, const float* __restrict__ dinv,
        const int* __restrict__ rowptr, const unsigned* __restrict__ csr,
        const float* __restrict__ b2, const float* __restrict__ Wc,
        const int* __restrict__ batch,
        float* __restrict__ gsum, int* __restrict__ gcnt, int N) {
    __shared__ float sb2[H];
    __shared__ float swc[H];
    int t = threadIdx.x;
    if (t < H) { sb2[t] = b2[t]; swc[t] = Wc[t]; }
    __syncthreads();
    int grp = t >> 4;
    int l16 = t & 15;
    int node = blockIdx.x * 16 + grp;
    if (node >= N) return;
    float acc[8];
#pragma unroll
    for (int j = 0; j < 8; j++) acc[j] = 0.f;
    int beg = rowptr[node], end = rowptr[node + 1];
    for (int i = beg; i < end; i += 4) {
        int rem = end - i;
        unsigned c0 = csr[i];
        unsigned c1 = (rem > 1) ? csr[i + 1] : 0u;
        unsigned c2 = (rem > 2) ? csr[i + 2] : 0u;
        unsigned c3 = (rem > 3) ? csr[i + 3] : 0u;
        uint4 p0 = hB4[(size_t)(c0 & SRC_MASK) * 16 + l16];
        uint4 p1 = hB4[(size_t)(c1 & SRC_MASK) * 16 + l16];
        uint4 p2 = hB4[(size_t)(c2 & SRC_MASK) * 16 + l16];
        uint4 p3 = hB4[(size_t)(c3 & SRC_MASK) * 16 + l16];
        acc8(acc, p0, (float)(c0 >> 17) * WSCALE);
        acc8(acc, p1, (float)(c1 >> 17) * WSCALE);
        acc8(acc, p2, (float)(c2 >> 17) * WSCALE);
        acc8(acc, p3, (float)(c3 >> 17) * WSCALE);
    }
    float di = dinv[node];
    uint4 ps = hB4[(size_t)node * 16 + l16];
    acc8(acc, ps, di * di);
    float dot = 0.f;
#pragma unroll
    for (int j = 0; j < 8; j++) {
        float v = fmaxf(acc[j] + sb2[8 * l16 + j], 0.f);
        dot += v * swc[8 * l16 + j];
    }
    dot += __shfl_xor(dot, 1);
    dot += __shfl_xor(dot, 2);
    dot += __shfl_xor(dot, 4);
    dot += __shfl_xor(dot, 8);
    if (l16 == 0) {
        int gidx = batch[node];
        atomAddF(&gsum[gidx], dot);
        atomicAdd(&gcnt[gidx], 1);
    }
}

__global__ void out_kernel(const float* __restrict__ gsum, const int* __restrict__ gcnt,
                           const float* __restrict__ bc, float* __restrict__ out, int G) {
    int g = blockIdx.x * blockDim.x + threadIdx.x;
    if (g >= G) return;
    float c = fmaxf((float)gcnt[g], 1.f);
    float logit = gsum[g] / c + bc[0];
    out[g] = 1.f / (1.f + expf(-logit));
}

extern "C" void kernel_launch(void* const* d_in, const int* in_sizes, int n_in,
                              void* d_out, int out_size, void* d_ws, size_t ws_size,
                              hipStream_t stream) {
    const float* x     = (const float*)d_in[0];
    const int*   ei    = (const int*)d_in[1];
    const int*   batch = (const int*)d_in[2];
    const float* W1    = (const float*)d_in[3];
    const float* b1    = (const float*)d_in[4];
    const float* W2    = (const float*)d_in[5];
    const float* b2    = (const float*)d_in[6];
    const float* Wc    = (const float*)d_in[7];
    const float* bc    = (const float*)d_in[8];
    float* out = (float*)d_out;

    int N = in_sizes[2];
    int E = in_sizes[1] / 2;
    int G = out_size;
    int NB = (N + CHUNK - 1) / CHUNK;

    char* ws = (char*)d_ws;
    size_t off = 0;
    auto alloc = [&](size_t bytes) {
        void* p = ws + off;
        off += (bytes + 255) & ~(size_t)255;
        return p;
    };
    __hip_bfloat16* hBb = (__hip_bfloat16*)alloc((size_t)N * H * sizeof(__hip_bfloat16));
    float* aggx   = (float*)alloc((size_t)N * 3 * sizeof(float));
    // deg/gsum/gcnt contiguous -> single memset
    int*   deg    = (int*)  alloc((size_t)N * sizeof(int));
    float* gsum   = (float*)alloc((size_t)G * sizeof(float));
    int*   gcnt   = (int*)  alloc((size_t)G * sizeof(int));
    char*  zero_end = ws + off;
    int*   rowptr = (int*)  alloc((size_t)(N + 1) * sizeof(int));
    int*   cursor = (int*)  alloc((size_t)N * sizeof(int));
    float* dinv   = (float*)alloc((size_t)N * sizeof(float));
    unsigned* csr = (unsigned*)alloc((size_t)E * sizeof(unsigned));
    __hip_bfloat16* Bp = (__hip_bfloat16*)alloc((size_t)H * H * sizeof(__hip_bfloat16));
    int*   partial= (int*)  alloc((size_t)NB * sizeof(int));
    int*   pscan  = (int*)  alloc((size_t)NB * sizeof(int));

    (void)hipMemsetAsync(deg, 0, (size_t)(zero_end - (char*)deg), stream);

    {
        int nthr4 = (E + 3) / 4;
        deg_kernel<<<(nthr4 + NTPB - 1) / NTPB, NTPB, 0, stream>>>(ei, E, deg);
    }

    scan_partial<<<NB, NTPB, 0, stream>>>(deg, N, partial);
    scan_tops<<<1, 128, 0, stream>>>(partial, NB, pscan, rowptr, N);
    scan_apply<<<NB, NTPB, 0, stream>>>(deg, N, pscan, rowptr, cursor, dinv);

    {
        int nthr4 = (E + 3) / 4;
        scatter_kernel<<<(nthr4 + NTPB - 1) / NTPB, NTPB, 0, stream>>>(ei, E, dinv, cursor, csr);
    }

    bpack_kernel<<<8, NTPB, 0, stream>>>(W2, Bp);

    l1_gather<<<(N + NTPB - 1) / NTPB, NTPB, 0, stream>>>(x, dinv, rowptr, csr, aggx, N);

    {
        int ntiles = (N + 15) / 16;
        gemm2_mfma<<<(ntiles + 3) / 4, NTPB, 0, stream>>>(aggx, W1, b1, Bp, hBb, N);
    }

    gather_pool<<<(N + 15) / 16, NTPB, 0, stream>>>(
        (const uint4*)hBb, dinv, rowptr, csr, b2, Wc, batch, gsum, gcnt, N);

    out_kernel<<<(G + NTPB - 1) / NTPB, NTPB, 0, stream>>>(gsum, gcnt, bc, out, G);
}

// Round 11
// 451.279 us; speedup vs baseline: 1.2209x; 1.1954x over previous
//
#include <hip/hip_runtime.h>
#include <hip/hip_bf16.h>
#include <math.h>

#define H 128
#define NTPB 256
#define CHUNK 1024  // elements per scan block (256 threads x 4)
#define SRC_MASK 0x1FFFFu
#define WSCALE (1.0f / 32767.0f)

typedef __attribute__((ext_vector_type(8))) short short8;
typedef __attribute__((ext_vector_type(4))) float floatx4;

__device__ __forceinline__ void atomAddF(float* p, float v) {
    __hip_atomic_fetch_add(p, v, __ATOMIC_RELAXED, __HIP_MEMORY_SCOPE_AGENT);
}

__device__ __forceinline__ short f2bf(float v) {
    __hip_bfloat16 b = __float2bfloat16(v);
    return __builtin_bit_cast(short, b);
}

// accumulate one 256B bf16 row chunk (uint4 = 8 bf16) scaled by wgt
__device__ __forceinline__ void acc8(float* acc, uint4 p, float wgt) {
    acc[0] += __uint_as_float(p.x << 16) * wgt;
    acc[1] += __uint_as_float(p.x & 0xffff0000u) * wgt;
    acc[2] += __uint_as_float(p.y << 16) * wgt;
    acc[3] += __uint_as_float(p.y & 0xffff0000u) * wgt;
    acc[4] += __uint_as_float(p.z << 16) * wgt;
    acc[5] += __uint_as_float(p.z & 0xffff0000u) * wgt;
    acc[6] += __uint_as_float(p.w << 16) * wgt;
    acc[7] += __uint_as_float(p.w & 0xffff0000u) * wgt;
}

// deg[d] = number of in-edges (1 edge/thread: max waves to hide atomic latency;
// the int4 4-edge variant measured ~+50us on the tail, R8-R10)
__global__ void deg_kernel(const int* __restrict__ ei, int E, int* __restrict__ deg) {
    int e = blockIdx.x * blockDim.x + threadIdx.x;
    if (e < E) atomicAdd(&deg[ei[E + e]], 1);
}

// ---- exclusive scan of deg -> rowptr ----
__global__ void scan_partial(const int* __restrict__ deg, int N, int* __restrict__ partial) {
    __shared__ int sd[NTPB];
    int b = blockIdx.x, t = threadIdx.x;
    int base = b * CHUNK + t * 4;
    int s = 0;
#pragma unroll
    for (int k = 0; k < 4; k++) { int i = base + k; if (i < N) s += deg[i]; }
    sd[t] = s; __syncthreads();
    for (int off = NTPB / 2; off > 0; off >>= 1) {
        if (t < off) sd[t] += sd[t + off];
        __syncthreads();
    }
    if (t == 0) partial[b] = sd[0];
}

// wave-parallel scan of block sums (nb <= 128); also writes rowptr[N] = E
__global__ void scan_tops(const int* __restrict__ partial, int nb,
                          int* __restrict__ pscan, int* __restrict__ rowptr, int N) {
    __shared__ int sd[128];
    int t = threadIdx.x;
    int v = (t < nb) ? partial[t] : 0;
    sd[t] = v; __syncthreads();
    for (int s = 1; s < 128; s <<= 1) {
        int u = (t >= s) ? sd[t - s] : 0;
        __syncthreads();
        sd[t] += u;
        __syncthreads();
    }
    if (t < nb) pscan[t] = sd[t] - v;  // exclusive
    if (t == 0) rowptr[N] = sd[127];
}

// also emits dinv
__global__ void scan_apply(const int* __restrict__ deg, int N, const int* __restrict__ pscan,
                           int* __restrict__ rowptr, int* __restrict__ cursor,
                           float* __restrict__ dinv) {
    __shared__ int sd[NTPB];
    int b = blockIdx.x, t = threadIdx.x;
    int base = b * CHUNK + t * 4;
    int d0 = 0, d1 = 0, d2 = 0, d3 = 0;
    if (base + 0 < N) d0 = deg[base + 0];
    if (base + 1 < N) d1 = deg[base + 1];
    if (base + 2 < N) d2 = deg[base + 2];
    if (base + 3 < N) d3 = deg[base + 3];
    int tsum = d0 + d1 + d2 + d3;
    sd[t] = tsum; __syncthreads();
    for (int s = 1; s < NTPB; s <<= 1) {
        int v = (t >= s) ? sd[t - s] : 0;
        __syncthreads();
        sd[t] += v;
        __syncthreads();
    }
    int p0 = sd[t] - tsum + pscan[b];
    int p1 = p0 + d0, p2 = p1 + d1, p3 = p2 + d2;
    if (base + 0 < N) { rowptr[base + 0] = p0; cursor[base + 0] = p0; dinv[base + 0] = rsqrtf((float)(d0 + 1)); }
    if (base + 1 < N) { rowptr[base + 1] = p1; cursor[base + 1] = p1; dinv[base + 1] = rsqrtf((float)(d1 + 1)); }
    if (base + 2 < N) { rowptr[base + 2] = p2; cursor[base + 2] = p2; dinv[base + 2] = rsqrtf((float)(d2 + 1)); }
    if (base + 3 < N) { rowptr[base + 3] = p3; cursor[base + 3] = p3; dinv[base + 3] = rsqrtf((float)(d3 + 1)); }
}

// bucket-scatter: dst-grouped packed edge = (w*32767)<<17 | src (1 edge/thread)
__global__ void scatter_kernel(const int* __restrict__ ei, int E, const float* __restrict__ dinv,
                               int* __restrict__ cursor, unsigned* __restrict__ csr) {
    int e = blockIdx.x * blockDim.x + threadIdx.x;
    if (e >= E) return;
    int s = ei[e], d = ei[E + e];
    int pos = atomicAdd(&cursor[d], 1);
    float w = dinv[s] * dinv[d];
    csr[pos] = ((unsigned)(w * 32767.0f + 0.5f) << 17) | (unsigned)s;
}

// pre-pack W2 into bf16 B-fragments for mfma_f32_16x16x32_bf16
__global__ void bpack_kernel(const float* __restrict__ W2, __hip_bfloat16* __restrict__ Bp) {
    int idx = blockIdx.x * blockDim.x + threadIdx.x;  // 0..2047
    if (idx >= 2048) return;
    int frag = idx >> 6, lane = idx & 63;
    int nt = frag >> 2, c = frag & 3, quad = lane >> 4, m16 = lane & 15;
#pragma unroll
    for (int jj = 0; jj < 8; jj++) {
        int k = c * 32 + quad * 8 + jj;
        Bp[idx * 8 + jj] = __float2bfloat16(W2[k * H + nt * 16 + m16]);
    }
}

// layer-1 CSR gather on raw x (3-wide), 4-edge unroll, packed csr  (R7-proven form)
__global__ void l1_gather(const float* __restrict__ x, const float* __restrict__ dinv,
                          const int* __restrict__ rowptr, const unsigned* __restrict__ csr,
                          float* __restrict__ aggx, int N) {
    int n = blockIdx.x * blockDim.x + threadIdx.x;
    if (n >= N) return;
    float di = dinv[n], d2 = di * di;
    float a0 = x[3 * n + 0] * d2, a1 = x[3 * n + 1] * d2, a2 = x[3 * n + 2] * d2;
    int beg = rowptr[n], end = rowptr[n + 1];
    int i = beg;
    for (; i + 4 <= end; i += 4) {
        unsigned c0 = csr[i], c1 = csr[i + 1], c2 = csr[i + 2], c3 = csr[i + 3];
        int s0 = c0 & SRC_MASK, s1 = c1 & SRC_MASK, s2 = c2 & SRC_MASK, s3 = c3 & SRC_MASK;
        float w0 = (float)(c0 >> 17) * WSCALE, w1 = (float)(c1 >> 17) * WSCALE;
        float w2 = (float)(c2 >> 17) * WSCALE, w3 = (float)(c3 >> 17) * WSCALE;
        float x00 = x[3 * s0], x01 = x[3 * s0 + 1], x02 = x[3 * s0 + 2];
        float x10 = x[3 * s1], x11 = x[3 * s1 + 1], x12 = x[3 * s1 + 2];
        float x20 = x[3 * s2], x21 = x[3 * s2 + 1], x22 = x[3 * s2 + 2];
        float x30 = x[3 * s3], x31 = x[3 * s3 + 1], x32 = x[3 * s3 + 2];
        a0 += x00 * w0 + x10 * w1 + x20 * w2 + x30 * w3;
        a1 += x01 * w0 + x11 * w1 + x21 * w2 + x31 * w3;
        a2 += x02 * w0 + x12 * w1 + x22 * w2 + x32 * w3;
    }
    for (; i < end; ++i) {
        unsigned c = csr[i];
        int s = c & SRC_MASK;
        float w = (float)(c >> 17) * WSCALE;
        a0 += x[3 * s + 0] * w;
        a1 += x[3 * s + 1] * w;
        a2 += x[3 * s + 2] * w;
    }
    aggx[3 * n + 0] = a0; aggx[3 * n + 1] = a1; aggx[3 * n + 2] = a2;
}

// MFMA gemm: one wave per 16-row tile. A = relu(aggx@W1+b1) built in regs (bf16),
// B = pre-packed W2 frags, D -> bf16 hB.
__global__ void gemm2_mfma(const float* __restrict__ aggx, const float* __restrict__ W1,
                           const float* __restrict__ b1, const __hip_bfloat16* __restrict__ Bp,
                           __hip_bfloat16* __restrict__ hBb, int N) {
    int wave = threadIdx.x >> 6, lane = threadIdx.x & 63;
    int quad = lane >> 4, m16 = lane & 15;
    int tile = blockIdx.x * 4 + wave;
    int rowbase = tile * 16;
    if (rowbase >= N) return;
    int m = rowbase + m16;
    float a0 = 0.f, a1 = 0.f, a2 = 0.f;
    if (m < N) { a0 = aggx[3 * m]; a1 = aggx[3 * m + 1]; a2 = aggx[3 * m + 2]; }
    short8 af[4];
#pragma unroll
    for (int c = 0; c < 4; c++) {
#pragma unroll
        for (int jj = 0; jj < 8; jj++) {
            int k = c * 32 + quad * 8 + jj;
            float h = fmaxf(a0 * W1[k] + a1 * W1[H + k] + a2 * W1[2 * H + k] + b1[k], 0.f);
            af[c][jj] = f2bf(h);
        }
    }
    const short8* bp = (const short8*)Bp;
    floatx4 acc[8];
#pragma unroll
    for (int nt = 0; nt < 8; nt++) acc[nt] = (floatx4){0.f, 0.f, 0.f, 0.f};
#pragma unroll
    for (int nt = 0; nt < 8; nt++) {
#pragma unroll
        for (int c = 0; c < 4; c++) {
            short8 bf = bp[(nt * 4 + c) * 64 + lane];
            acc[nt] = __builtin_amdgcn_mfma_f32_16x16x32_bf16(af[c], bf, acc[nt], 0, 0, 0);
        }
    }
#pragma unroll
    for (int nt = 0; nt < 8; nt++) {
#pragma unroll
        for (int reg = 0; reg < 4; reg++) {
            int row = rowbase + quad * 4 + reg;
            int col = nt * 16 + m16;
            if (row < N) hBb[(size_t)row * H + col] = __float2bfloat16(acc[nt][reg]);
        }
    }
}

// layer-2 gather: one 16-lane group per NODE (4 nodes/wave). Row read = 16 lanes
// x uint4 (256 B). 4-edge unroll. At the random-line service wall (~222us floor;
// six structurally different variants R2-R10 all land 222-260us).
__global__ __launch_bounds__(NTPB, 8) void gather_pool(
        const uint4* __restrict__ hB4, const float* __restrict__ dinv,
        const int* __restrict__ rowptr, const unsigned* __restrict__ csr,
        const float* __restrict__ b2, const float* __restrict__ Wc,
        const int* __restrict__ batch,
        float* __restrict__ gsum, int* __restrict__ gcnt, int N) {
    __shared__ float sb2[H];
    __shared__ float swc[H];
    int t = threadIdx.x;
    if (t < H) { sb2[t] = b2[t]; swc[t] = Wc[t]; }
    __syncthreads();
    int grp = t >> 4;
    int l16 = t & 15;
    int node = blockIdx.x * 16 + grp;
    if (node >= N) return;
    float acc[8];
#pragma unroll
    for (int j = 0; j < 8; j++) acc[j] = 0.f;
    int beg = rowptr[node], end = rowptr[node + 1];
    for (int i = beg; i < end; i += 4) {
        int rem = end - i;
        unsigned c0 = csr[i];
        unsigned c1 = (rem > 1) ? csr[i + 1] : 0u;
        unsigned c2 = (rem > 2) ? csr[i + 2] : 0u;
        unsigned c3 = (rem > 3) ? csr[i + 3] : 0u;
        uint4 p0 = hB4[(size_t)(c0 & SRC_MASK) * 16 + l16];
        uint4 p1 = hB4[(size_t)(c1 & SRC_MASK) * 16 + l16];
        uint4 p2 = hB4[(size_t)(c2 & SRC_MASK) * 16 + l16];
        uint4 p3 = hB4[(size_t)(c3 & SRC_MASK) * 16 + l16];
        acc8(acc, p0, (float)(c0 >> 17) * WSCALE);
        acc8(acc, p1, (float)(c1 >> 17) * WSCALE);
        acc8(acc, p2, (float)(c2 >> 17) * WSCALE);
        acc8(acc, p3, (float)(c3 >> 17) * WSCALE);
    }
    float di = dinv[node];
    uint4 ps = hB4[(size_t)node * 16 + l16];
    acc8(acc, ps, di * di);
    float dot = 0.f;
#pragma unroll
    for (int j = 0; j < 8; j++) {
        float v = fmaxf(acc[j] + sb2[8 * l16 + j], 0.f);
        dot += v * swc[8 * l16 + j];
    }
    dot += __shfl_xor(dot, 1);
    dot += __shfl_xor(dot, 2);
    dot += __shfl_xor(dot, 4);
    dot += __shfl_xor(dot, 8);
    if (l16 == 0) {
        int gidx = batch[node];
        atomAddF(&gsum[gidx], dot);
        atomicAdd(&gcnt[gidx], 1);
    }
}

__global__ void out_kernel(const float* __restrict__ gsum, const int* __restrict__ gcnt,
                           const float* __restrict__ bc, float* __restrict__ out, int G) {
    int g = blockIdx.x * blockDim.x + threadIdx.x;
    if (g >= G) return;
    float c = fmaxf((float)gcnt[g], 1.f);
    float logit = gsum[g] / c + bc[0];
    out[g] = 1.f / (1.f + expf(-logit));
}

extern "C" void kernel_launch(void* const* d_in, const int* in_sizes, int n_in,
                              void* d_out, int out_size, void* d_ws, size_t ws_size,
                              hipStream_t stream) {
    const float* x     = (const float*)d_in[0];
    const int*   ei    = (const int*)d_in[1];
    const int*   batch = (const int*)d_in[2];
    const float* W1    = (const float*)d_in[3];
    const float* b1    = (const float*)d_in[4];
    const float* W2    = (const float*)d_in[5];
    const float* b2    = (const float*)d_in[6];
    const float* Wc    = (const float*)d_in[7];
    const float* bc    = (const float*)d_in[8];
    float* out = (float*)d_out;

    int N = in_sizes[2];
    int E = in_sizes[1] / 2;
    int G = out_size;
    int NB = (N + CHUNK - 1) / CHUNK;

    char* ws = (char*)d_ws;
    size_t off = 0;
    auto alloc = [&](size_t bytes) {
        void* p = ws + off;
        off += (bytes + 255) & ~(size_t)255;
        return p;
    };
    __hip_bfloat16* hBb = (__hip_bfloat16*)alloc((size_t)N * H * sizeof(__hip_bfloat16));
    float* aggx   = (float*)alloc((size_t)N * 3 * sizeof(float));
    // deg/gsum/gcnt contiguous -> single memset
    int*   deg    = (int*)  alloc((size_t)N * sizeof(int));
    float* gsum   = (float*)alloc((size_t)G * sizeof(float));
    int*   gcnt   = (int*)  alloc((size_t)G * sizeof(int));
    char*  zero_end = ws + off;
    int*   rowptr = (int*)  alloc((size_t)(N + 1) * sizeof(int));
    int*   cursor = (int*)  alloc((size_t)N * sizeof(int));
    float* dinv   = (float*)alloc((size_t)N * sizeof(float));
    unsigned* csr = (unsigned*)alloc((size_t)E * sizeof(unsigned));
    __hip_bfloat16* Bp = (__hip_bfloat16*)alloc((size_t)H * H * sizeof(__hip_bfloat16));
    int*   partial= (int*)  alloc((size_t)NB * sizeof(int));
    int*   pscan  = (int*)  alloc((size_t)NB * sizeof(int));

    (void)hipMemsetAsync(deg, 0, (size_t)(zero_end - (char*)deg), stream);

    deg_kernel<<<(E + NTPB - 1) / NTPB, NTPB, 0, stream>>>(ei, E, deg);

    scan_partial<<<NB, NTPB, 0, stream>>>(deg, N, partial);
    scan_tops<<<1, 128, 0, stream>>>(partial, NB, pscan, rowptr, N);
    scan_apply<<<NB, NTPB, 0, stream>>>(deg, N, pscan, rowptr, cursor, dinv);

    scatter_kernel<<<(E + NTPB - 1) / NTPB, NTPB, 0, stream>>>(ei, E, dinv, cursor, csr);

    bpack_kernel<<<8, NTPB, 0, stream>>>(W2, Bp);

    l1_gather<<<(N + NTPB - 1) / NTPB, NTPB, 0, stream>>>(x, dinv, rowptr, csr, aggx, N);

    {
        int ntiles = (N + 15) / 16;
        gemm2_mfma<<<(ntiles + 3) / 4, NTPB, 0, stream>>>(aggx, W1, b1, Bp, hBb, N);
    }

    gather_pool<<<(N + 15) / 16, NTPB, 0, stream>>>(
        (const uint4*)hBb, dinv, rowptr, csr, b2, Wc, batch, gsum, gcnt, N);

    out_kernel<<<(G + NTPB - 1) / NTPB, NTPB, 0, stream>>>(gsum, gcnt, bc, out, G);
}